// Round 5
// baseline (211.968 us; speedup 1.0000x reference)
//
#include <hip/hip_runtime.h>

// Instant-NGP hash-grid encode. Round-5: R4 balanced schedule + xyz moved
// off the vector-request pipe (LDS staging) + easy-levels-fused blocks.
//
// Cost model (validated R0-R4):
// - Binding resource: per-XCD vector-memory REQUEST ISSUE rate,
//   ~37.5 G req/s/XCD (16 req/cyc @2.34GHz). R0 (4.46M req/XCD, 125us)
//   and R4 (4.19M, 112us) both sit at 96-97% of it with different L1-hit
//   mixes -> EVERY request counts (TA rate), L1-hit or not.
// - R3 confound resolved: its -9% requests was cancelled by halved wave
//   count (VGPR 72). Request cuts must preserve occupancy.
// - R4 proven: stride-8 interleaved phase-2 (identical level mix per XCD)
//   is balanced by construction; levels stay synchronized so each XCD L2
//   holds one table at a time.
// - R2: 8B stores to out pay 32B HBM sectors; keep level-major ws + 16us
//   LDS transpose.
// This round (-12% requests at constant occupancy):
// - LDS-stage xyz per 512-pt chunk: 384x16B cooperative loads replace 768
//   per-thread loads; coord re-reads go to the idle LDS pipe.
//   xyz: 1.5 -> 0.75 req/pt-lvl.
// - Fuse levels 0-5 into one "M" block kind looping 6 levels over the same
//   staged chunk (combined tables ~2.2MB: L2-resident; xyz cost /6).
//   Phase-2 item list [L7xC | L6xC | MxC], stride-8 across XCDs.
// Per-XCD: 1.90M (phase1) + 0.24M (L7) + 0.24M (L6) + 1.30M (M) = 3.68M
// req vs R4 4.19M -> predicted gather ~98-102us.
//
// Kept invariants (proven):
// - x-paired 16B gathers: 4 unconditional vf4 + avg 2 predicated vf2 per
//   point-level (6 table req/pt-lvl = the floor for this hash).
// - NO agent-scope/sc0 loads (bypass per-XCD L2).
// - Pin gather results live via empty asm (else compiler sinks loads).
// - 2 pts/thread, keep VGPR in the <=64 wave class.
// - nt stores for bulk output (don't evict the pinned table from L2).

#define HG_N_LEVELS   16
#define HG_TABLE_SIZE 524288u
#define HG_TABLE_MASK (HG_TABLE_SIZE - 1u)

typedef float vf2 __attribute__((ext_vector_type(2)));
typedef float vf4 __attribute__((ext_vector_type(4)));

// Per-point prep: 4 yz-hash partials + weights + x0.
__device__ __forceinline__ void hg_prep2(
    float px, float py, float pz, float res,
    unsigned* __restrict__ s, float* __restrict__ wyz,
    unsigned* __restrict__ x0out, float* __restrict__ wx)
{
    const float lim = 1.0f - 1e-6f;
    float ux = fminf(fmaxf(px + 0.5f, 0.0f), lim);
    float uy = fminf(fmaxf(py + 0.5f, 0.0f), lim);
    float uz = fminf(fmaxf(pz + 0.5f, 0.0f), lim);
    float fx = ux * res, fy = uy * res, fz = uz * res;
    float x0f = floorf(fx), y0f = floorf(fy), z0f = floorf(fz);
    float wx1 = fx - x0f, wy1 = fy - y0f, wz1 = fz - z0f;
    float wx0 = 1.0f - wx1, wy0 = 1.0f - wy1, wz0 = 1.0f - wz1;
    unsigned x0 = (unsigned)x0f, y0 = (unsigned)y0f, z0 = (unsigned)z0f;
    const unsigned P1 = 2654435761u, P2 = 805459861u;
    unsigned hy0 = y0 * P1, hy1 = (y0 + 1u) * P1;
    unsigned hz0 = z0 * P2, hz1 = (z0 + 1u) * P2;
    s[0] = hy0 ^ hz0;  wyz[0] = wy0 * wz0;
    s[1] = hy0 ^ hz1;  wyz[1] = wy0 * wz1;
    s[2] = hy1 ^ hz0;  wyz[2] = wy1 * wz0;
    s[3] = hy1 ^ hz1;  wyz[3] = wy1 * wz1;
    *x0out = x0; wx[0] = wx0; wx[1] = wx1;
}

// Legacy full-prep for fallback/tail paths.
__device__ __forceinline__ void hg_prep(
    float px, float py, float pz, float res,
    unsigned* __restrict__ idx, float* __restrict__ w)
{
    unsigned s[4]; float wyz[4], wx[2]; unsigned x0;
    hg_prep2(px, py, pz, res, s, wyz, &x0, wx);
    #pragma unroll
    for (int j = 0; j < 4; ++j) {
        idx[j]     = (x0 ^ s[j]) & HG_TABLE_MASK;        w[j]     = wx[0] * wyz[j];
        idx[4 + j] = ((x0 + 1u) ^ s[j]) & HG_TABLE_MASK; w[4 + j] = wx[1] * wyz[j];
    }
}

// Scalar single-point gather (tail path).
__device__ __forceinline__ vf2 hg_gather1(
    const float2* __restrict__ tbl, float res,
    float px, float py, float pz)
{
    unsigned idx[8]; float w[8];
    hg_prep(px, py, pz, res, idx, w);
    vf2 f[8];
    #pragma unroll
    for (int k = 0; k < 8; ++k) f[k] = *(const vf2*)(tbl + idx[k]);
    float sx = 0.f, sy = 0.f;
    #pragma unroll
    for (int k = 0; k < 8; ++k) { sx += w[k] * f[k].x; sy += w[k] * f[k].y; }
    vf2 v; v.x = sx; v.y = sy;
    return v;
}

// Two-point gather for one level: returns {oax, oay, obx, oby}.
// x-paired 16B loads + predicated 8B odd loads + asm pin (proven structure).
__device__ __forceinline__ vf4 hg_gather2(
    const float2* __restrict__ tbl, float res,
    float ax, float ay, float az, float bx, float by, float bz)
{
    unsigned sA[4], sB[4], x0A, x0B;
    float wyzA[4], wyzB[4], wxA[2], wxB[2];
    hg_prep2(ax, ay, az, res, sA, wyzA, &x0A, wxA);
    hg_prep2(bx, by, bz, res, sB, wyzB, &x0B, wxB);

    unsigned iA0[4], iA1[4], iB0[4], iB1[4];
    #pragma unroll
    for (int j = 0; j < 4; ++j) {
        iA0[j] = (x0A ^ sA[j]) & HG_TABLE_MASK;
        iA1[j] = ((x0A + 1u) ^ sA[j]) & HG_TABLE_MASK;
        iB0[j] = (x0B ^ sB[j]) & HG_TABLE_MASK;
        iB1[j] = ((x0B + 1u) ^ sB[j]) & HG_TABLE_MASK;
    }
    const bool oddA = (x0A & 1u) != 0u;
    const bool oddB = (x0B & 1u) != 0u;

    vf4 qA[4], qB[4];
    #pragma unroll
    for (int j = 0; j < 4; ++j) qA[j] = *(const vf4*)(tbl + (iA0[j] & ~1u));
    #pragma unroll
    for (int j = 0; j < 4; ++j) qB[j] = *(const vf4*)(tbl + (iB0[j] & ~1u));

    vf2 eA[4], eB[4];
    #pragma unroll
    for (int j = 0; j < 4; ++j) { eA[j] = (vf2)(0.f); eB[j] = (vf2)(0.f); }
    if (oddA) {
        #pragma unroll
        for (int j = 0; j < 4; ++j) eA[j] = *(const vf2*)(tbl + iA1[j]);
    }
    if (oddB) {
        #pragma unroll
        for (int j = 0; j < 4; ++j) eB[j] = *(const vf2*)(tbl + iB1[j]);
    }

    asm volatile(""
        : "+v"(qA[0]), "+v"(qA[1]), "+v"(qA[2]), "+v"(qA[3]),
          "+v"(qB[0]), "+v"(qB[1]), "+v"(qB[2]), "+v"(qB[3]),
          "+v"(eA[0]), "+v"(eA[1]), "+v"(eA[2]), "+v"(eA[3]),
          "+v"(eB[0]), "+v"(eB[1]), "+v"(eB[2]), "+v"(eB[3])
        :
        : "memory");

    float oax = 0.f, oay = 0.f, obx = 0.f, oby = 0.f;
    #pragma unroll
    for (int j = 0; j < 4; ++j) {
        bool hi = (iA0[j] & 1u) != 0u;
        vf2 lo;  lo.x  = qA[j].x; lo.y  = qA[j].y;
        vf2 hiv; hiv.x = qA[j].z; hiv.y = qA[j].w;
        vf2 f0 = hi ? hiv : lo;                  // corner x-offset 0
        vf2 f1 = oddA ? eA[j] : (hi ? lo : hiv); // corner x-offset 1
        float w0 = wxA[0] * wyzA[j], w1 = wxA[1] * wyzA[j];
        oax += w0 * f0.x + w1 * f1.x;
        oay += w0 * f0.y + w1 * f1.y;
    }
    #pragma unroll
    for (int j = 0; j < 4; ++j) {
        bool hi = (iB0[j] & 1u) != 0u;
        vf2 lo;  lo.x  = qB[j].x; lo.y  = qB[j].y;
        vf2 hiv; hiv.x = qB[j].z; hiv.y = qB[j].w;
        vf2 f0 = hi ? hiv : lo;
        vf2 f1 = oddB ? eB[j] : (hi ? lo : hiv);
        float w0 = wxB[0] * wyzB[j], w1 = wxB[1] * wyzB[j];
        obx += w0 * f0.x + w1 * f1.x;
        oby += w0 * f0.y + w1 * f1.y;
    }

    vf4 r; r.x = oax; r.y = oay; r.z = obx; r.w = oby;
    return r;
}

// ---------- Phase 1: balanced XCD-phased gather -> ws [16][N] ----------
// Block kinds: single-level (phase-1 hard levels, L7, L6) and M (levels 0-5
// looped over one staged chunk). xyz staged in LDS once per block.
__global__ __launch_bounds__(256) void hashgrid_gather_lvl(
    const float* __restrict__ xyz,
    const float* __restrict__ tables,
    const int*   __restrict__ resolutions,
    float*       __restrict__ ws,       // [16][n] float2, as floats
    int n_points)
{
    const int x    = blockIdx.x & 7;    // XCD (blockIdx%8 round-robin)
    const int slot = blockIdx.x >> 3;   // position in XCD x's work queue
    const int C    = (n_points + 511) >> 9;  // 512-point chunks per level

    // Phase 1 (slot < C): level 8+x exclusively (one 4MB table per XCD L2).
    // Phase 2: flat item list [L7 x C | L6 x C | M x C], XCD x takes items
    //   g = (slot-C)*8 + x -> every XCD gets 1/8 of every item type:
    //   balanced by construction, level-synchronized across XCDs.
    int kind = 0;                       // 0: single level, 1: multi (0-5)
    int level = 0, chunk;
    if (slot < C) {
        level = 8 + x; chunk = slot;
    } else {
        int g = ((slot - C) << 3) + x;  // [0, 3C)
        if (g >= 3 * C) return;
        int d = g / C;                  // 0:L7, 1:L6, 2:M
        chunk = g - d * C;
        if (d == 0)      level = 7;
        else if (d == 1) level = 6;
        else             kind = 1;
    }

    const int base = chunk << 9;
    if (base >= n_points) return;
    const int t = (int)threadIdx.x;

    // ---- cooperative xyz staging: 512 pts * 12B = 6144B = 384 x 16B ----
    __shared__ float sxyz[1536];
    const bool full = (base + 512 <= n_points);
    if (full) {
        const vf4* __restrict__ src = (const vf4*)(xyz + (size_t)base * 3);
        vf4* dst = (vf4*)sxyz;
        dst[t] = src[t];
        if (t < 128) dst[256 + t] = src[256 + t];
        __syncthreads();
    }

    if (kind == 0) {
        const float res = (float)resolutions[level];
        const float2* __restrict__ tbl =
            (const float2*)tables + (size_t)level * HG_TABLE_SIZE;
        float* __restrict__ wlev = ws + (size_t)level * n_points * 2;

        if (full) {
            const float* lp = sxyz + 6 * t;      // 2 points = 6 floats
            vf2 c0 = *(const vf2*)(lp);
            vf2 c1 = *(const vf2*)(lp + 2);
            vf2 c2 = *(const vf2*)(lp + 4);
            const int p0 = base + 2 * t;
            vf4 v = hg_gather2(tbl, res, c0.x, c0.y, c1.x, c1.y, c2.x, c2.y);
            __builtin_nontemporal_store(v, (vf4*)(wlev + 2 * (size_t)p0));
        } else {
            // ragged tail chunk: per-point direct loads
            for (int p = base + t; p < n_points; p += 256) {
                vf2 v = hg_gather1(tbl, res,
                                   xyz[(size_t)p * 3 + 0],
                                   xyz[(size_t)p * 3 + 1],
                                   xyz[(size_t)p * 3 + 2]);
                __builtin_nontemporal_store(v, (vf2*)(wlev + 2 * (size_t)p));
            }
        }
    } else {
        // ---- M block: loop easy levels 0..5 over the staged chunk ----
        if (full) {
            const float* lp = sxyz + 6 * t;
            vf2 c0 = *(const vf2*)(lp);
            vf2 c1 = *(const vf2*)(lp + 2);
            vf2 c2 = *(const vf2*)(lp + 4);
            const int p0 = base + 2 * t;
            #pragma unroll 1
            for (int lev = 0; lev < 6; ++lev) {
                const float res = (float)resolutions[lev];
                const float2* __restrict__ tbl =
                    (const float2*)tables + (size_t)lev * HG_TABLE_SIZE;
                float* __restrict__ wlev = ws + (size_t)lev * n_points * 2;
                vf4 v = hg_gather2(tbl, res, c0.x, c0.y, c1.x, c1.y, c2.x, c2.y);
                __builtin_nontemporal_store(v, (vf4*)(wlev + 2 * (size_t)p0));
            }
        } else {
            #pragma unroll 1
            for (int lev = 0; lev < 6; ++lev) {
                const float res = (float)resolutions[lev];
                const float2* __restrict__ tbl =
                    (const float2*)tables + (size_t)lev * HG_TABLE_SIZE;
                float* __restrict__ wlev = ws + (size_t)lev * n_points * 2;
                for (int p = base + t; p < n_points; p += 256) {
                    vf2 v = hg_gather1(tbl, res,
                                       xyz[(size_t)p * 3 + 0],
                                       xyz[(size_t)p * 3 + 1],
                                       xyz[(size_t)p * 3 + 2]);
                    __builtin_nontemporal_store(v, (vf2*)(wlev + 2 * (size_t)p));
                }
            }
        }
    }
}

// ---------- Phase 2: transpose ws [16][N] -> out [N][16], float4 both sides ----------
#define TP_PTS 256
#define TP_STRIDE (2 * TP_PTS + 4)   // floats per LDS row (pad 4 -> <=2-way conflicts)

__global__ __launch_bounds__(256) void hashgrid_transpose(
    const float* __restrict__ ws,
    float*       __restrict__ out,
    int n_points)
{
    __shared__ float tile[16 * TP_STRIDE];   // ~33 KB, level-major
    const int p0 = blockIdx.x * TP_PTS;
    const int t  = (int)threadIdx.x;
    const int npts = min(TP_PTS, n_points - p0);

    #pragma unroll
    for (int it = 0; it < 8; ++it) {
        int r  = it * 2 + (t >> 7);
        int q  = t & 127;
        int pt = q * 2;
        if (pt < npts) {
            const float* src = ws + (size_t)r * n_points * 2 + (size_t)(p0 + pt) * 2;
            vf4 v;
            if (pt + 1 < npts) v = *(const vf4*)src;
            else { vf2 v2 = *(const vf2*)src; v.x = v2.x; v.y = v2.y; v.z = 0.f; v.w = 0.f; }
            *(vf4*)&tile[r * TP_STRIDE + 4 * q] = v;
        }
    }
    __syncthreads();

    #pragma unroll
    for (int it = 0; it < 8; ++it) {
        int linear = it * 256 + t;
        int pt = linear >> 3;
        int v4 = linear & 7;
        if (pt < npts) {
            vf4 v;
            #pragma unroll
            for (int k = 0; k < 4; ++k) {
                int e = 4 * v4 + k;
                int lev = e >> 1, f = e & 1;
                v[k] = tile[lev * TP_STRIDE + 2 * pt + f];
            }
            __builtin_nontemporal_store(
                v, (vf4*)(out + (size_t)(p0 + pt) * 32 + 4 * v4));
        }
    }
}

// ---------- Fallback: single-kernel version ----------
__global__ __launch_bounds__(256) void hashgrid_fwd(
    const float* __restrict__ xyz,
    const float* __restrict__ tables,
    const int*   __restrict__ resolutions,
    float*       __restrict__ out,
    int n_points)
{
    int tid   = blockIdx.x * blockDim.x + threadIdx.x;
    int point = tid >> 4;
    int level = tid & 15;
    if (point >= n_points) return;

    float px = xyz[point * 3 + 0];
    float py = xyz[point * 3 + 1];
    float pz = xyz[point * 3 + 2];
    float res = (float)resolutions[level];
    const float2* __restrict__ tbl =
        (const float2*)tables + (size_t)level * HG_TABLE_SIZE;

    vf2 v = hg_gather1(tbl, res, px, py, pz);
    *(vf2*)(out + (size_t)point * 32 + 2 * level) = v;
}

extern "C" void kernel_launch(void* const* d_in, const int* in_sizes, int n_in,
                              void* d_out, int out_size, void* d_ws, size_t ws_size,
                              hipStream_t stream) {
    const float* xyz         = (const float*)d_in[0];
    const float* tables      = (const float*)d_in[1];
    const int*   resolutions = (const int*)d_in[2];
    float*       out         = (float*)d_out;

    int n_points = in_sizes[0] / 3;
    size_t ws_needed = (size_t)n_points * HG_N_LEVELS * sizeof(float2);

    if (ws_size >= ws_needed) {
        float* ws = (float*)d_ws;
        int C  = (n_points + 511) >> 9;
        int S2 = (3 * C + 7) >> 3;       // phase-2 slots per XCD
        int slots = C + S2;
        hashgrid_gather_lvl<<<8 * slots, 256, 0, stream>>>(
            xyz, tables, resolutions, ws, n_points);
        int tblocks = (n_points + TP_PTS - 1) / TP_PTS;
        hashgrid_transpose<<<tblocks, 256, 0, stream>>>(ws, out, n_points);
    } else {
        int n_threads = n_points * HG_N_LEVELS;
        hashgrid_fwd<<<(n_threads + 255) / 256, 256, 0, stream>>>(
            xyz, tables, resolutions, out, n_points);
    }
}

// Round 6
// 207.942 us; speedup vs baseline: 1.0194x; 1.0194x over previous
//
#include <hip/hip_runtime.h>

// Instant-NGP hash-grid encode. Round-6: R5's request budget (LDS-staged
// xyz + fused easy levels) with the scheduling bug fixed: longest block
// quanta FIRST, fine-grained quanta last.
//
// Cost model (validated R0-R5):
// - Binding resource: per-XCD vector-memory request issue, ~37.4 G req/s
//   (16 req/cyc @2.34GHz) when the queue drains evenly (R4: 97%).
// - R5 lesson: putting the 6-level fused "M" blocks (~20us quanta) at the
//   END of each XCD queue starved the drain (last 64 items / 32 CUs = 2
//   blocks/CU for the final ~40us; occupancy 61->40%, efficiency 82%).
//   Longest jobs must go first; the tail must be 1-chunk quanta.
// - R4: stride-8 interleaved phase-2 with identical per-XCD mix is
//   balanced by construction and keeps levels synchronized (one table per
//   XCD L2 at a time).
// - R3: request cuts must not sacrifice occupancy (VGPR <= 64 class).
// - R2: 8B stores to out pay 32B HBM sectors (4x write amp); keep
//   level-major ws (16B stores) + 16us LDS transpose.
// This round:
// - Phase-2 item list [Ma x C | Mb x C | L7 x C | L6 x C], stride-8 across
//   XCDs. Ma = levels 3-5 fused, Mb = levels 0-2 fused (3-level quanta,
//   ~3x standard -> less skew than 6x), L7/L6 = single chunks (tail).
// - Requests/XCD: 1.90M (phase1, staged) + 0.66M (Ma) + 0.66M (Mb)
//   + 0.24M (L7) + 0.24M (L6) = 3.70M -> predicted ~100-106us gather.
//
// Kept invariants (proven):
// - x-paired 16B gathers: 4 unconditional vf4 + avg 2 predicated vf2 per
//   point-level (6 table req/pt-lvl = floor for this hash).
// - LDS-staged xyz per 512-pt chunk (384x16B cooperative loads, re-reads
//   on the idle LDS pipe): 0.75 req/pt-lvl single-level, /3 when fused.
// - NO agent-scope/sc0 loads (bypass per-XCD L2).
// - Pin gather results live via empty asm (else compiler sinks loads).
// - nt stores for bulk output (don't evict the pinned table from L2).

#define HG_N_LEVELS   16
#define HG_TABLE_SIZE 524288u
#define HG_TABLE_MASK (HG_TABLE_SIZE - 1u)

typedef float vf2 __attribute__((ext_vector_type(2)));
typedef float vf4 __attribute__((ext_vector_type(4)));

// Per-point prep: 4 yz-hash partials + weights + x0.
__device__ __forceinline__ void hg_prep2(
    float px, float py, float pz, float res,
    unsigned* __restrict__ s, float* __restrict__ wyz,
    unsigned* __restrict__ x0out, float* __restrict__ wx)
{
    const float lim = 1.0f - 1e-6f;
    float ux = fminf(fmaxf(px + 0.5f, 0.0f), lim);
    float uy = fminf(fmaxf(py + 0.5f, 0.0f), lim);
    float uz = fminf(fmaxf(pz + 0.5f, 0.0f), lim);
    float fx = ux * res, fy = uy * res, fz = uz * res;
    float x0f = floorf(fx), y0f = floorf(fy), z0f = floorf(fz);
    float wx1 = fx - x0f, wy1 = fy - y0f, wz1 = fz - z0f;
    float wx0 = 1.0f - wx1, wy0 = 1.0f - wy1, wz0 = 1.0f - wz1;
    unsigned x0 = (unsigned)x0f, y0 = (unsigned)y0f, z0 = (unsigned)z0f;
    const unsigned P1 = 2654435761u, P2 = 805459861u;
    unsigned hy0 = y0 * P1, hy1 = (y0 + 1u) * P1;
    unsigned hz0 = z0 * P2, hz1 = (z0 + 1u) * P2;
    s[0] = hy0 ^ hz0;  wyz[0] = wy0 * wz0;
    s[1] = hy0 ^ hz1;  wyz[1] = wy0 * wz1;
    s[2] = hy1 ^ hz0;  wyz[2] = wy1 * wz0;
    s[3] = hy1 ^ hz1;  wyz[3] = wy1 * wz1;
    *x0out = x0; wx[0] = wx0; wx[1] = wx1;
}

// Legacy full-prep for fallback/tail paths.
__device__ __forceinline__ void hg_prep(
    float px, float py, float pz, float res,
    unsigned* __restrict__ idx, float* __restrict__ w)
{
    unsigned s[4]; float wyz[4], wx[2]; unsigned x0;
    hg_prep2(px, py, pz, res, s, wyz, &x0, wx);
    #pragma unroll
    for (int j = 0; j < 4; ++j) {
        idx[j]     = (x0 ^ s[j]) & HG_TABLE_MASK;        w[j]     = wx[0] * wyz[j];
        idx[4 + j] = ((x0 + 1u) ^ s[j]) & HG_TABLE_MASK; w[4 + j] = wx[1] * wyz[j];
    }
}

// Scalar single-point gather (tail path).
__device__ __forceinline__ vf2 hg_gather1(
    const float2* __restrict__ tbl, float res,
    float px, float py, float pz)
{
    unsigned idx[8]; float w[8];
    hg_prep(px, py, pz, res, idx, w);
    vf2 f[8];
    #pragma unroll
    for (int k = 0; k < 8; ++k) f[k] = *(const vf2*)(tbl + idx[k]);
    float sx = 0.f, sy = 0.f;
    #pragma unroll
    for (int k = 0; k < 8; ++k) { sx += w[k] * f[k].x; sy += w[k] * f[k].y; }
    vf2 v; v.x = sx; v.y = sy;
    return v;
}

// Two-point gather for one level: returns {oax, oay, obx, oby}.
// x-paired 16B loads + predicated 8B odd loads + asm pin (proven structure).
__device__ __forceinline__ vf4 hg_gather2(
    const float2* __restrict__ tbl, float res,
    float ax, float ay, float az, float bx, float by, float bz)
{
    unsigned sA[4], sB[4], x0A, x0B;
    float wyzA[4], wyzB[4], wxA[2], wxB[2];
    hg_prep2(ax, ay, az, res, sA, wyzA, &x0A, wxA);
    hg_prep2(bx, by, bz, res, sB, wyzB, &x0B, wxB);

    unsigned iA0[4], iA1[4], iB0[4], iB1[4];
    #pragma unroll
    for (int j = 0; j < 4; ++j) {
        iA0[j] = (x0A ^ sA[j]) & HG_TABLE_MASK;
        iA1[j] = ((x0A + 1u) ^ sA[j]) & HG_TABLE_MASK;
        iB0[j] = (x0B ^ sB[j]) & HG_TABLE_MASK;
        iB1[j] = ((x0B + 1u) ^ sB[j]) & HG_TABLE_MASK;
    }
    const bool oddA = (x0A & 1u) != 0u;
    const bool oddB = (x0B & 1u) != 0u;

    vf4 qA[4], qB[4];
    #pragma unroll
    for (int j = 0; j < 4; ++j) qA[j] = *(const vf4*)(tbl + (iA0[j] & ~1u));
    #pragma unroll
    for (int j = 0; j < 4; ++j) qB[j] = *(const vf4*)(tbl + (iB0[j] & ~1u));

    vf2 eA[4], eB[4];
    #pragma unroll
    for (int j = 0; j < 4; ++j) { eA[j] = (vf2)(0.f); eB[j] = (vf2)(0.f); }
    if (oddA) {
        #pragma unroll
        for (int j = 0; j < 4; ++j) eA[j] = *(const vf2*)(tbl + iA1[j]);
    }
    if (oddB) {
        #pragma unroll
        for (int j = 0; j < 4; ++j) eB[j] = *(const vf2*)(tbl + iB1[j]);
    }

    asm volatile(""
        : "+v"(qA[0]), "+v"(qA[1]), "+v"(qA[2]), "+v"(qA[3]),
          "+v"(qB[0]), "+v"(qB[1]), "+v"(qB[2]), "+v"(qB[3]),
          "+v"(eA[0]), "+v"(eA[1]), "+v"(eA[2]), "+v"(eA[3]),
          "+v"(eB[0]), "+v"(eB[1]), "+v"(eB[2]), "+v"(eB[3])
        :
        : "memory");

    float oax = 0.f, oay = 0.f, obx = 0.f, oby = 0.f;
    #pragma unroll
    for (int j = 0; j < 4; ++j) {
        bool hi = (iA0[j] & 1u) != 0u;
        vf2 lo;  lo.x  = qA[j].x; lo.y  = qA[j].y;
        vf2 hiv; hiv.x = qA[j].z; hiv.y = qA[j].w;
        vf2 f0 = hi ? hiv : lo;                  // corner x-offset 0
        vf2 f1 = oddA ? eA[j] : (hi ? lo : hiv); // corner x-offset 1
        float w0 = wxA[0] * wyzA[j], w1 = wxA[1] * wyzA[j];
        oax += w0 * f0.x + w1 * f1.x;
        oay += w0 * f0.y + w1 * f1.y;
    }
    #pragma unroll
    for (int j = 0; j < 4; ++j) {
        bool hi = (iB0[j] & 1u) != 0u;
        vf2 lo;  lo.x  = qB[j].x; lo.y  = qB[j].y;
        vf2 hiv; hiv.x = qB[j].z; hiv.y = qB[j].w;
        vf2 f0 = hi ? hiv : lo;
        vf2 f1 = oddB ? eB[j] : (hi ? lo : hiv);
        float w0 = wxB[0] * wyzB[j], w1 = wxB[1] * wyzB[j];
        obx += w0 * f0.x + w1 * f1.x;
        oby += w0 * f0.y + w1 * f1.y;
    }

    vf4 r; r.x = oax; r.y = oay; r.z = obx; r.w = oby;
    return r;
}

// ---------- Phase 1: balanced XCD-phased gather -> ws [16][N] ----------
// Block kinds: single-level (phase-1 hard levels, L7, L6), Ma (levels 3-5),
// Mb (levels 0-2). xyz staged in LDS once per block.
__global__ __launch_bounds__(256) void hashgrid_gather_lvl(
    const float* __restrict__ xyz,
    const float* __restrict__ tables,
    const int*   __restrict__ resolutions,
    float*       __restrict__ ws,       // [16][n] float2, as floats
    int n_points)
{
    const int x    = blockIdx.x & 7;    // XCD (blockIdx%8 round-robin)
    const int slot = blockIdx.x >> 3;   // position in XCD x's work queue
    const int C    = (n_points + 511) >> 9;  // 512-point chunks per level

    // Phase 1 (slot < C): level 8+x exclusively (one 4MB table per XCD L2).
    // Phase 2: flat item list [Ma x C | Mb x C | L7 x C | L6 x C], XCD x
    //   takes items g = (slot-C)*8 + x. Longest quanta (Ma/Mb, 3 levels)
    //   first; single-chunk L7/L6 drain the tail evenly.
    int lev_lo = 0, lev_n = 1, chunk;
    if (slot < C) {
        lev_lo = 8 + x; chunk = slot;
    } else {
        int g = ((slot - C) << 3) + x;  // [0, 4C)
        if (g >= 4 * C) return;
        int d = g / C;                  // 0:Ma, 1:Mb, 2:L7, 3:L6
        chunk = g - d * C;
        if (d == 0)      { lev_lo = 3; lev_n = 3; }
        else if (d == 1) { lev_lo = 0; lev_n = 3; }
        else if (d == 2) { lev_lo = 7; }
        else             { lev_lo = 6; }
    }

    const int base = chunk << 9;
    if (base >= n_points) return;
    const int t = (int)threadIdx.x;

    // ---- cooperative xyz staging: 512 pts * 12B = 6144B = 384 x 16B ----
    __shared__ float sxyz[1536];
    const bool full = (base + 512 <= n_points);
    if (full) {
        const vf4* __restrict__ src = (const vf4*)(xyz + (size_t)base * 3);
        vf4* dst = (vf4*)sxyz;
        dst[t] = src[t];
        if (t < 128) dst[256 + t] = src[256 + t];
        __syncthreads();
    }

    if (full) {
        const float* lp = sxyz + 6 * t;      // 2 points = 6 floats
        vf2 c0 = *(const vf2*)(lp);
        vf2 c1 = *(const vf2*)(lp + 2);
        vf2 c2 = *(const vf2*)(lp + 4);
        const int p0 = base + 2 * t;
        #pragma unroll 1
        for (int lev = lev_lo; lev < lev_lo + lev_n; ++lev) {
            const float res = (float)resolutions[lev];
            const float2* __restrict__ tbl =
                (const float2*)tables + (size_t)lev * HG_TABLE_SIZE;
            float* __restrict__ wlev = ws + (size_t)lev * n_points * 2;
            vf4 v = hg_gather2(tbl, res, c0.x, c0.y, c1.x, c1.y, c2.x, c2.y);
            __builtin_nontemporal_store(v, (vf4*)(wlev + 2 * (size_t)p0));
        }
    } else {
        // ragged tail chunk: per-point direct loads
        #pragma unroll 1
        for (int lev = lev_lo; lev < lev_lo + lev_n; ++lev) {
            const float res = (float)resolutions[lev];
            const float2* __restrict__ tbl =
                (const float2*)tables + (size_t)lev * HG_TABLE_SIZE;
            float* __restrict__ wlev = ws + (size_t)lev * n_points * 2;
            for (int p = base + t; p < n_points; p += 256) {
                vf2 v = hg_gather1(tbl, res,
                                   xyz[(size_t)p * 3 + 0],
                                   xyz[(size_t)p * 3 + 1],
                                   xyz[(size_t)p * 3 + 2]);
                __builtin_nontemporal_store(v, (vf2*)(wlev + 2 * (size_t)p));
            }
        }
    }
}

// ---------- Phase 2: transpose ws [16][N] -> out [N][16], float4 both sides ----------
#define TP_PTS 256
#define TP_STRIDE (2 * TP_PTS + 4)   // floats per LDS row (pad 4 -> <=2-way conflicts)

__global__ __launch_bounds__(256) void hashgrid_transpose(
    const float* __restrict__ ws,
    float*       __restrict__ out,
    int n_points)
{
    __shared__ float tile[16 * TP_STRIDE];   // ~33 KB, level-major
    const int p0 = blockIdx.x * TP_PTS;
    const int t  = (int)threadIdx.x;
    const int npts = min(TP_PTS, n_points - p0);

    #pragma unroll
    for (int it = 0; it < 8; ++it) {
        int r  = it * 2 + (t >> 7);
        int q  = t & 127;
        int pt = q * 2;
        if (pt < npts) {
            const float* src = ws + (size_t)r * n_points * 2 + (size_t)(p0 + pt) * 2;
            vf4 v;
            if (pt + 1 < npts) v = *(const vf4*)src;
            else { vf2 v2 = *(const vf2*)src; v.x = v2.x; v.y = v2.y; v.z = 0.f; v.w = 0.f; }
            *(vf4*)&tile[r * TP_STRIDE + 4 * q] = v;
        }
    }
    __syncthreads();

    #pragma unroll
    for (int it = 0; it < 8; ++it) {
        int linear = it * 256 + t;
        int pt = linear >> 3;
        int v4 = linear & 7;
        if (pt < npts) {
            vf4 v;
            #pragma unroll
            for (int k = 0; k < 4; ++k) {
                int e = 4 * v4 + k;
                int lev = e >> 1, f = e & 1;
                v[k] = tile[lev * TP_STRIDE + 2 * pt + f];
            }
            __builtin_nontemporal_store(
                v, (vf4*)(out + (size_t)(p0 + pt) * 32 + 4 * v4));
        }
    }
}

// ---------- Fallback: single-kernel version ----------
__global__ __launch_bounds__(256) void hashgrid_fwd(
    const float* __restrict__ xyz,
    const float* __restrict__ tables,
    const int*   __restrict__ resolutions,
    float*       __restrict__ out,
    int n_points)
{
    int tid   = blockIdx.x * blockDim.x + threadIdx.x;
    int point = tid >> 4;
    int level = tid & 15;
    if (point >= n_points) return;

    float px = xyz[point * 3 + 0];
    float py = xyz[point * 3 + 1];
    float pz = xyz[point * 3 + 2];
    float res = (float)resolutions[level];
    const float2* __restrict__ tbl =
        (const float2*)tables + (size_t)level * HG_TABLE_SIZE;

    vf2 v = hg_gather1(tbl, res, px, py, pz);
    *(vf2*)(out + (size_t)point * 32 + 2 * level) = v;
}

extern "C" void kernel_launch(void* const* d_in, const int* in_sizes, int n_in,
                              void* d_out, int out_size, void* d_ws, size_t ws_size,
                              hipStream_t stream) {
    const float* xyz         = (const float*)d_in[0];
    const float* tables      = (const float*)d_in[1];
    const int*   resolutions = (const int*)d_in[2];
    float*       out         = (float*)d_out;

    int n_points = in_sizes[0] / 3;
    size_t ws_needed = (size_t)n_points * HG_N_LEVELS * sizeof(float2);

    if (ws_size >= ws_needed) {
        float* ws = (float*)d_ws;
        int C  = (n_points + 511) >> 9;
        int S2 = (4 * C + 7) >> 3;       // phase-2 slots per XCD
        int slots = C + S2;
        hashgrid_gather_lvl<<<8 * slots, 256, 0, stream>>>(
            xyz, tables, resolutions, ws, n_points);
        int tblocks = (n_points + TP_PTS - 1) / TP_PTS;
        hashgrid_transpose<<<tblocks, 256, 0, stream>>>(ws, out, n_points);
    } else {
        int n_threads = n_points * HG_N_LEVELS;
        hashgrid_fwd<<<(n_threads + 255) / 256, 256, 0, stream>>>(
            xyz, tables, resolutions, out, n_points);
    }
}

// Round 7
// 204.460 us; speedup vs baseline: 1.0367x; 1.0170x over previous
//
#include <hip/hip_runtime.h>

// Instant-NGP hash-grid encode. Round-7: two kernels.
//   K1 "gather_hard": R4's EXACT proven structure (97% request-issue
//      efficiency) restricted to the 10 hard levels (8+x phase, then
//      stride-8 [L7|L6]) -> ws rows 6..15.
//   K2 "finalize": per 256-pt block, gather easy levels 0-5 directly into
//      the LDS transpose tile (their tables total ~2.2MB -> L2-resident on
//      every XCD, no pinning needed), cooperatively read ws rows 6..15
//      into the tile, write full-line transposed output.
// Deletes the easy-level ws round-trip and the standalone transpose.
//
// Cost model (validated R0-R6):
// - Binding resource: per-XCD vector-memory request issue, ~37.4 G req/s;
//   R4's plain block structure measures 97% of it; LDS-staging/fusion
//   variants (R5/R6) only reach 82-90% -> use plain structure for the
//   hard levels that carry 83% of requests.
// - R4: stride-8 interleaved phase-2 is balanced by construction; levels
//   stay synchronized so each XCD L2 holds one hard table at a time.
// - R5/R6: long fused quanta at the queue tail starve the drain.
//   K1's tail is single-chunk L7/L6 items; K2 is uniform small blocks.
// - R2: 8B-granular stores to out pay 32B HBM sectors (4x write amp);
//   K2 writes full 128B lines via the LDS tile (proven transpose path).
// - Budget/XCD: K1 = 2.62M req (~70us @97%), K2 = 1.63M (~45-50us).
//
// Kept invariants (proven):
// - x-paired 16B gathers: corners (x0,..),(x0+1,..) share an aligned 16B
//   line when x0 even -> 4 unconditional vf4 + avg 2 predicated vf2 per
//   point-level (6 table req/pt-lvl = floor for this hash).
// - NO agent-scope/sc0 loads (bypass per-XCD L2).
// - Pin gather results live via empty asm (else compiler sinks loads).
// - VGPR <= 64 wave class in gather kernels.
// - nt stores for bulk output; nt loads for read-once ws rows.

#define HG_N_LEVELS   16
#define HG_TABLE_SIZE 524288u
#define HG_TABLE_MASK (HG_TABLE_SIZE - 1u)

typedef float vf2 __attribute__((ext_vector_type(2)));
typedef float vf4 __attribute__((ext_vector_type(4)));

// Per-point prep: 4 yz-hash partials + weights + x0.
__device__ __forceinline__ void hg_prep2(
    float px, float py, float pz, float res,
    unsigned* __restrict__ s, float* __restrict__ wyz,
    unsigned* __restrict__ x0out, float* __restrict__ wx)
{
    const float lim = 1.0f - 1e-6f;
    float ux = fminf(fmaxf(px + 0.5f, 0.0f), lim);
    float uy = fminf(fmaxf(py + 0.5f, 0.0f), lim);
    float uz = fminf(fmaxf(pz + 0.5f, 0.0f), lim);
    float fx = ux * res, fy = uy * res, fz = uz * res;
    float x0f = floorf(fx), y0f = floorf(fy), z0f = floorf(fz);
    float wx1 = fx - x0f, wy1 = fy - y0f, wz1 = fz - z0f;
    float wx0 = 1.0f - wx1, wy0 = 1.0f - wy1, wz0 = 1.0f - wz1;
    unsigned x0 = (unsigned)x0f, y0 = (unsigned)y0f, z0 = (unsigned)z0f;
    const unsigned P1 = 2654435761u, P2 = 805459861u;
    unsigned hy0 = y0 * P1, hy1 = (y0 + 1u) * P1;
    unsigned hz0 = z0 * P2, hz1 = (z0 + 1u) * P2;
    s[0] = hy0 ^ hz0;  wyz[0] = wy0 * wz0;
    s[1] = hy0 ^ hz1;  wyz[1] = wy0 * wz1;
    s[2] = hy1 ^ hz0;  wyz[2] = wy1 * wz0;
    s[3] = hy1 ^ hz1;  wyz[3] = wy1 * wz1;
    *x0out = x0; wx[0] = wx0; wx[1] = wx1;
}

// Legacy full-prep for fallback/tail paths.
__device__ __forceinline__ void hg_prep(
    float px, float py, float pz, float res,
    unsigned* __restrict__ idx, float* __restrict__ w)
{
    unsigned s[4]; float wyz[4], wx[2]; unsigned x0;
    hg_prep2(px, py, pz, res, s, wyz, &x0, wx);
    #pragma unroll
    for (int j = 0; j < 4; ++j) {
        idx[j]     = (x0 ^ s[j]) & HG_TABLE_MASK;        w[j]     = wx[0] * wyz[j];
        idx[4 + j] = ((x0 + 1u) ^ s[j]) & HG_TABLE_MASK; w[4 + j] = wx[1] * wyz[j];
    }
}

// Scalar single-point gather, unpaired (fallback/tail path).
__device__ __forceinline__ vf2 hg_gather1(
    const float2* __restrict__ tbl, float res,
    float px, float py, float pz)
{
    unsigned idx[8]; float w[8];
    hg_prep(px, py, pz, res, idx, w);
    vf2 f[8];
    #pragma unroll
    for (int k = 0; k < 8; ++k) f[k] = *(const vf2*)(tbl + idx[k]);
    float sx = 0.f, sy = 0.f;
    #pragma unroll
    for (int k = 0; k < 8; ++k) { sx += w[k] * f[k].x; sy += w[k] * f[k].y; }
    vf2 v; v.x = sx; v.y = sy;
    return v;
}

// Single-point gather with x-pairing + pin (K2's per-level workhorse).
__device__ __forceinline__ vf2 hg_gather1p(
    const float2* __restrict__ tbl, float res,
    float px, float py, float pz)
{
    unsigned s[4], x0; float wyz[4], wx[2];
    hg_prep2(px, py, pz, res, s, wyz, &x0, wx);
    unsigned i0[4], i1[4];
    #pragma unroll
    for (int j = 0; j < 4; ++j) {
        i0[j] = (x0 ^ s[j]) & HG_TABLE_MASK;
        i1[j] = ((x0 + 1u) ^ s[j]) & HG_TABLE_MASK;
    }
    const bool odd = (x0 & 1u) != 0u;

    vf4 q[4];
    #pragma unroll
    for (int j = 0; j < 4; ++j) q[j] = *(const vf4*)(tbl + (i0[j] & ~1u));
    vf2 e[4];
    #pragma unroll
    for (int j = 0; j < 4; ++j) e[j] = (vf2)(0.f);
    if (odd) {
        #pragma unroll
        for (int j = 0; j < 4; ++j) e[j] = *(const vf2*)(tbl + i1[j]);
    }
    asm volatile(""
        : "+v"(q[0]), "+v"(q[1]), "+v"(q[2]), "+v"(q[3]),
          "+v"(e[0]), "+v"(e[1]), "+v"(e[2]), "+v"(e[3])
        :
        : "memory");

    float ox = 0.f, oy = 0.f;
    #pragma unroll
    for (int j = 0; j < 4; ++j) {
        bool hi = (i0[j] & 1u) != 0u;
        vf2 lo;  lo.x  = q[j].x; lo.y  = q[j].y;
        vf2 hiv; hiv.x = q[j].z; hiv.y = q[j].w;
        vf2 f0 = hi ? hiv : lo;                 // corner x-offset 0
        vf2 f1 = odd ? e[j] : (hi ? lo : hiv);  // corner x-offset 1
        float w0 = wx[0] * wyz[j], w1 = wx[1] * wyz[j];
        ox += w0 * f0.x + w1 * f1.x;
        oy += w0 * f0.y + w1 * f1.y;
    }
    vf2 r; r.x = ox; r.y = oy;
    return r;
}

// ---------- K1: hard levels (6..15) -> ws rows 6..15, R4-exact structure ----------
__global__ __launch_bounds__(256) void hashgrid_gather_hard(
    const float* __restrict__ xyz,
    const float* __restrict__ tables,
    const int*   __restrict__ resolutions,
    float*       __restrict__ ws,       // [16][n] float2, as floats
    int n_points)
{
    const int x    = blockIdx.x & 7;    // XCD (blockIdx%8 round-robin)
    const int slot = blockIdx.x >> 3;   // position in XCD x's work queue
    const int C    = (n_points + 511) >> 9;  // 512-point chunks per level

    // Phase 1 (slot < C): level 8+x exclusively (one 4MB table per XCD L2).
    // Phase 2: flat item list [L7 x C | L6 x C], XCD x takes items
    //   g = (slot-C)*8 + x -> every XCD gets 1/8 of each, single-chunk
    //   quanta drain the tail evenly.
    int level, chunk;
    if (slot < C) {
        level = 8 + x; chunk = slot;
    } else {
        int g = ((slot - C) << 3) + x;  // [0, 2C)
        if (g >= 2 * C) return;
        int d = g / C;                  // 0:L7, 1:L6
        level = 7 - d;
        chunk = g - d * C;
    }
    if (chunk >= C) return;

    const float res = (float)resolutions[level];
    const float2* __restrict__ tbl =
        (const float2*)tables + (size_t)level * HG_TABLE_SIZE;
    float* __restrict__ wlev = ws + (size_t)level * n_points * 2;

    const int p0 = (chunk << 9) + ((int)threadIdx.x << 1);   // 2 pts/thread
    if (p0 >= n_points) return;

    if (p0 + 1 < n_points) {
        const float* xp = xyz + (size_t)p0 * 3;
        vf2 c0 = *(const vf2*)(xp);
        vf2 c1 = *(const vf2*)(xp + 2);
        vf2 c2 = *(const vf2*)(xp + 4);

        unsigned sA[4], sB[4], x0A, x0B;
        float wyzA[4], wyzB[4], wxA[2], wxB[2];
        hg_prep2(c0.x, c0.y, c1.x, res, sA, wyzA, &x0A, wxA);
        hg_prep2(c1.y, c2.x, c2.y, res, sB, wyzB, &x0B, wxB);

        unsigned iA0[4], iA1[4], iB0[4], iB1[4];
        #pragma unroll
        for (int j = 0; j < 4; ++j) {
            iA0[j] = (x0A ^ sA[j]) & HG_TABLE_MASK;
            iA1[j] = ((x0A + 1u) ^ sA[j]) & HG_TABLE_MASK;
            iB0[j] = (x0B ^ sB[j]) & HG_TABLE_MASK;
            iB1[j] = ((x0B + 1u) ^ sB[j]) & HG_TABLE_MASK;
        }
        const bool oddA = (x0A & 1u) != 0u;
        const bool oddB = (x0B & 1u) != 0u;

        vf4 qA[4], qB[4];
        #pragma unroll
        for (int j = 0; j < 4; ++j) qA[j] = *(const vf4*)(tbl + (iA0[j] & ~1u));
        #pragma unroll
        for (int j = 0; j < 4; ++j) qB[j] = *(const vf4*)(tbl + (iB0[j] & ~1u));

        vf2 eA[4], eB[4];
        #pragma unroll
        for (int j = 0; j < 4; ++j) { eA[j] = (vf2)(0.f); eB[j] = (vf2)(0.f); }
        if (oddA) {
            #pragma unroll
            for (int j = 0; j < 4; ++j) eA[j] = *(const vf2*)(tbl + iA1[j]);
        }
        if (oddB) {
            #pragma unroll
            for (int j = 0; j < 4; ++j) eB[j] = *(const vf2*)(tbl + iB1[j]);
        }

        asm volatile(""
            : "+v"(qA[0]), "+v"(qA[1]), "+v"(qA[2]), "+v"(qA[3]),
              "+v"(qB[0]), "+v"(qB[1]), "+v"(qB[2]), "+v"(qB[3]),
              "+v"(eA[0]), "+v"(eA[1]), "+v"(eA[2]), "+v"(eA[3]),
              "+v"(eB[0]), "+v"(eB[1]), "+v"(eB[2]), "+v"(eB[3])
            :
            : "memory");

        float oax = 0.f, oay = 0.f, obx = 0.f, oby = 0.f;
        #pragma unroll
        for (int j = 0; j < 4; ++j) {
            bool hi = (iA0[j] & 1u) != 0u;
            vf2 lo;  lo.x  = qA[j].x; lo.y  = qA[j].y;
            vf2 hiv; hiv.x = qA[j].z; hiv.y = qA[j].w;
            vf2 f0 = hi ? hiv : lo;
            vf2 f1 = oddA ? eA[j] : (hi ? lo : hiv);
            float w0 = wxA[0] * wyzA[j], w1 = wxA[1] * wyzA[j];
            oax += w0 * f0.x + w1 * f1.x;
            oay += w0 * f0.y + w1 * f1.y;
        }
        #pragma unroll
        for (int j = 0; j < 4; ++j) {
            bool hi = (iB0[j] & 1u) != 0u;
            vf2 lo;  lo.x  = qB[j].x; lo.y  = qB[j].y;
            vf2 hiv; hiv.x = qB[j].z; hiv.y = qB[j].w;
            vf2 f0 = hi ? hiv : lo;
            vf2 f1 = oddB ? eB[j] : (hi ? lo : hiv);
            float w0 = wxB[0] * wyzB[j], w1 = wxB[1] * wyzB[j];
            obx += w0 * f0.x + w1 * f1.x;
            oby += w0 * f0.y + w1 * f1.y;
        }

        vf4 v; v.x = oax; v.y = oay; v.z = obx; v.w = oby;
        __builtin_nontemporal_store(v, (vf4*)(wlev + 2 * (size_t)p0));
    } else {
        float px = xyz[(size_t)p0 * 3 + 0];
        float py = xyz[(size_t)p0 * 3 + 1];
        float pz = xyz[(size_t)p0 * 3 + 2];
        vf2 v = hg_gather1(tbl, res, px, py, pz);
        __builtin_nontemporal_store(v, (vf2*)(wlev + 2 * (size_t)p0));
    }
}

// ---------- K2: easy gathers (0..5) + ws rows (6..15) -> out [N][16] ----------
#define TP_PTS 256
#define TP_STRIDE (2 * TP_PTS + 4)   // floats per LDS row (pad 4 -> <=2-way conflicts)

__global__ __launch_bounds__(256) void hashgrid_finalize(
    const float* __restrict__ xyz,
    const float* __restrict__ tables,
    const int*   __restrict__ resolutions,
    const float* __restrict__ ws,
    float*       __restrict__ out,
    int n_points)
{
    __shared__ float tile[16 * TP_STRIDE];   // ~33 KB, level-major
    __shared__ float sxyz[3 * TP_PTS];       // 3 KB staged coords
    const int p0 = blockIdx.x * TP_PTS;
    const int t  = (int)threadIdx.x;
    const int npts = min(TP_PTS, n_points - p0);
    const bool full = (npts == TP_PTS);

    // stage xyz: 256 pts * 12B = 3072B = 192 x 16B
    if (full) {
        const vf4* __restrict__ src = (const vf4*)(xyz + (size_t)p0 * 3);
        if (t < 192) ((vf4*)sxyz)[t] = src[t];
    } else {
        for (int p = t; p < npts; p += 256) {
            sxyz[3 * p + 0] = xyz[(size_t)(p0 + p) * 3 + 0];
            sxyz[3 * p + 1] = xyz[(size_t)(p0 + p) * 3 + 1];
            sxyz[3 * p + 2] = xyz[(size_t)(p0 + p) * 3 + 2];
        }
    }

    // cooperative ws rows 6..15 -> tile (1280 vf4 over 256 threads, 5 each)
    #pragma unroll
    for (int k = 0; k < 5; ++k) {
        int idx = t + k * 256;          // [0,1280)
        int r   = 6 + (idx >> 7);       // 6..15
        int q   = idx & 127;            // vf4 index within row (2 pts each)
        int pt  = q * 2;
        if (pt < npts) {
            const float* src = ws + (size_t)r * n_points * 2 + (size_t)(p0 + pt) * 2;
            vf4 v;
            if (pt + 1 < npts) v = __builtin_nontemporal_load((const vf4*)src);
            else { vf2 v2 = __builtin_nontemporal_load((const vf2*)src);
                   v.x = v2.x; v.y = v2.y; v.z = 0.f; v.w = 0.f; }
            *(vf4*)&tile[r * TP_STRIDE + 4 * q] = v;
        }
    }
    __syncthreads();   // sxyz ready

    // easy levels 0..5: thread t gathers point p0+t per level -> tile rows 0..5
    if (t < npts) {
        float px = sxyz[3 * t + 0];
        float py = sxyz[3 * t + 1];
        float pz = sxyz[3 * t + 2];
        #pragma unroll 1
        for (int lev = 0; lev < 6; ++lev) {
            const float res = (float)resolutions[lev];
            const float2* __restrict__ tbl =
                (const float2*)tables + (size_t)lev * HG_TABLE_SIZE;
            vf2 r = hg_gather1p(tbl, res, px, py, pz);
            *(vf2*)&tile[lev * TP_STRIDE + 2 * t] = r;
        }
    }
    __syncthreads();   // tile complete (ws rows + easy rows)

    // transposed write-out: full 128B lines, nt stores (proven path)
    #pragma unroll
    for (int it = 0; it < 8; ++it) {
        int linear = it * 256 + t;
        int pt = linear >> 3;
        int v4 = linear & 7;
        if (pt < npts) {
            vf4 v;
            #pragma unroll
            for (int k = 0; k < 4; ++k) {
                int e = 4 * v4 + k;
                int lev = e >> 1, f = e & 1;
                v[k] = tile[lev * TP_STRIDE + 2 * pt + f];
            }
            __builtin_nontemporal_store(
                v, (vf4*)(out + (size_t)(p0 + pt) * 32 + 4 * v4));
        }
    }
}

// ---------- Fallback: single-kernel version (ws too small) ----------
__global__ __launch_bounds__(256) void hashgrid_fwd(
    const float* __restrict__ xyz,
    const float* __restrict__ tables,
    const int*   __restrict__ resolutions,
    float*       __restrict__ out,
    int n_points)
{
    int tid   = blockIdx.x * blockDim.x + threadIdx.x;
    int point = tid >> 4;
    int level = tid & 15;
    if (point >= n_points) return;

    float px = xyz[point * 3 + 0];
    float py = xyz[point * 3 + 1];
    float pz = xyz[point * 3 + 2];
    float res = (float)resolutions[level];
    const float2* __restrict__ tbl =
        (const float2*)tables + (size_t)level * HG_TABLE_SIZE;

    vf2 v = hg_gather1(tbl, res, px, py, pz);
    *(vf2*)(out + (size_t)point * 32 + 2 * level) = v;
}

extern "C" void kernel_launch(void* const* d_in, const int* in_sizes, int n_in,
                              void* d_out, int out_size, void* d_ws, size_t ws_size,
                              hipStream_t stream) {
    const float* xyz         = (const float*)d_in[0];
    const float* tables      = (const float*)d_in[1];
    const int*   resolutions = (const int*)d_in[2];
    float*       out         = (float*)d_out;

    int n_points = in_sizes[0] / 3;
    size_t ws_needed = (size_t)n_points * HG_N_LEVELS * sizeof(float2);

    if (ws_size >= ws_needed) {
        float* ws = (float*)d_ws;
        int C  = (n_points + 511) >> 9;
        int S2 = (2 * C + 7) >> 3;       // phase-2 slots per XCD
        int slots = C + S2;
        hashgrid_gather_hard<<<8 * slots, 256, 0, stream>>>(
            xyz, tables, resolutions, ws, n_points);
        int fblocks = (n_points + TP_PTS - 1) / TP_PTS;
        hashgrid_finalize<<<fblocks, 256, 0, stream>>>(
            xyz, tables, resolutions, ws, out, n_points);
    } else {
        int n_threads = n_points * HG_N_LEVELS;
        hashgrid_fwd<<<(n_threads + 255) / 256, 256, 0, stream>>>(
            xyz, tables, resolutions, out, n_points);
    }
}

// Round 9
// 203.671 us; speedup vs baseline: 1.0407x; 1.0039x over previous
//
#include <hip/hip_runtime.h>

// Instant-NGP hash-grid encode. Round-9: resubmit of round-8 (bench infra
// failed; kernel unchanged). R7 two-kernel structure with phase-2
// cold-table replication halved (L7 -> XCDs 0-3, L6 -> XCDs 4-7).
//
//   K1 "gather_hard": R4's proven block structure on the 10 hard levels.
//      Phase 1: XCD x owns level 8+x (one 4MB table warm in its L2).
//      Phase 2: L7 chunks split stride-4 over XCDs 0-3; L6 over XCDs 4-7.
//      Each XCD: C + C/4 chunks, ONE cold table in phase 2 (was two),
//      replication 25MB (was 50MB: R7 FETCH 74MB, 86% issue efficiency;
//      the 11us gap to the 70us request floor is phase-2 cold misses).
//   K2 "finalize": per 256-pt block, gather easy levels 0-5 (tables total
//      ~2.2MB, L2-resident on every XCD) straight into the LDS transpose
//      tile, cooperatively read ws rows 6..15, write full-line output.
//      Measured ~44us ~= its 1.6M req/XCD floor. Unchanged.
//
// Cost model (validated R0-R7):
// - Binding resource: per-XCD vector-memory request issue, ~37.4 G req/s.
//   Request floor: K1 2.62M/XCD = 70us, K2 1.63M/XCD = 44us.
// - R7: K1 at 86% - deficit localized to phase-2 cold-miss window (both
//   L7+L6 fetched cold by all 8 XCDs). This round halves that.
// - R5/R6: LDS-staging xyz costs ~10% issue efficiency in gather blocks
//   (97 -> 87) and only saves 9% requests - a wash, rejected.
// - R3: request cuts must not drop VGPR wave class (<=64).
// - R2: 8B-granular stores to out pay 32B HBM sectors; K2's LDS-tile
//   full-line path is the proven write-out.
// - R1: whole-level XCD assignment of unequal-cost levels serializes;
//   split levels by chunks, balance by construction.
//
// Kept invariants (proven):
// - x-paired 16B gathers: corners (x0,..),(x0+1,..) share an aligned 16B
//   line when x0 even -> 4 unconditional vf4 + avg 2 predicated vf2 per
//   point-level (6 table req/pt-lvl = floor for this hash).
// - NO agent-scope/sc0 loads (bypass per-XCD L2).
// - Pin gather results live via empty asm (else compiler sinks loads).
// - nt stores for bulk output; nt loads for read-once ws rows.

#define HG_N_LEVELS   16
#define HG_TABLE_SIZE 524288u
#define HG_TABLE_MASK (HG_TABLE_SIZE - 1u)

typedef float vf2 __attribute__((ext_vector_type(2)));
typedef float vf4 __attribute__((ext_vector_type(4)));

// Per-point prep: 4 yz-hash partials + weights + x0.
__device__ __forceinline__ void hg_prep2(
    float px, float py, float pz, float res,
    unsigned* __restrict__ s, float* __restrict__ wyz,
    unsigned* __restrict__ x0out, float* __restrict__ wx)
{
    const float lim = 1.0f - 1e-6f;
    float ux = fminf(fmaxf(px + 0.5f, 0.0f), lim);
    float uy = fminf(fmaxf(py + 0.5f, 0.0f), lim);
    float uz = fminf(fmaxf(pz + 0.5f, 0.0f), lim);
    float fx = ux * res, fy = uy * res, fz = uz * res;
    float x0f = floorf(fx), y0f = floorf(fy), z0f = floorf(fz);
    float wx1 = fx - x0f, wy1 = fy - y0f, wz1 = fz - z0f;
    float wx0 = 1.0f - wx1, wy0 = 1.0f - wy1, wz0 = 1.0f - wz1;
    unsigned x0 = (unsigned)x0f, y0 = (unsigned)y0f, z0 = (unsigned)z0f;
    const unsigned P1 = 2654435761u, P2 = 805459861u;
    unsigned hy0 = y0 * P1, hy1 = (y0 + 1u) * P1;
    unsigned hz0 = z0 * P2, hz1 = (z0 + 1u) * P2;
    s[0] = hy0 ^ hz0;  wyz[0] = wy0 * wz0;
    s[1] = hy0 ^ hz1;  wyz[1] = wy0 * wz1;
    s[2] = hy1 ^ hz0;  wyz[2] = wy1 * wz0;
    s[3] = hy1 ^ hz1;  wyz[3] = wy1 * wz1;
    *x0out = x0; wx[0] = wx0; wx[1] = wx1;
}

// Legacy full-prep for fallback/tail paths.
__device__ __forceinline__ void hg_prep(
    float px, float py, float pz, float res,
    unsigned* __restrict__ idx, float* __restrict__ w)
{
    unsigned s[4]; float wyz[4], wx[2]; unsigned x0;
    hg_prep2(px, py, pz, res, s, wyz, &x0, wx);
    #pragma unroll
    for (int j = 0; j < 4; ++j) {
        idx[j]     = (x0 ^ s[j]) & HG_TABLE_MASK;        w[j]     = wx[0] * wyz[j];
        idx[4 + j] = ((x0 + 1u) ^ s[j]) & HG_TABLE_MASK; w[4 + j] = wx[1] * wyz[j];
    }
}

// Scalar single-point gather, unpaired (fallback/tail path).
__device__ __forceinline__ vf2 hg_gather1(
    const float2* __restrict__ tbl, float res,
    float px, float py, float pz)
{
    unsigned idx[8]; float w[8];
    hg_prep(px, py, pz, res, idx, w);
    vf2 f[8];
    #pragma unroll
    for (int k = 0; k < 8; ++k) f[k] = *(const vf2*)(tbl + idx[k]);
    float sx = 0.f, sy = 0.f;
    #pragma unroll
    for (int k = 0; k < 8; ++k) { sx += w[k] * f[k].x; sy += w[k] * f[k].y; }
    vf2 v; v.x = sx; v.y = sy;
    return v;
}

// Single-point gather with x-pairing + pin (K2's per-level workhorse).
__device__ __forceinline__ vf2 hg_gather1p(
    const float2* __restrict__ tbl, float res,
    float px, float py, float pz)
{
    unsigned s[4], x0; float wyz[4], wx[2];
    hg_prep2(px, py, pz, res, s, wyz, &x0, wx);
    unsigned i0[4], i1[4];
    #pragma unroll
    for (int j = 0; j < 4; ++j) {
        i0[j] = (x0 ^ s[j]) & HG_TABLE_MASK;
        i1[j] = ((x0 + 1u) ^ s[j]) & HG_TABLE_MASK;
    }
    const bool odd = (x0 & 1u) != 0u;

    vf4 q[4];
    #pragma unroll
    for (int j = 0; j < 4; ++j) q[j] = *(const vf4*)(tbl + (i0[j] & ~1u));
    vf2 e[4];
    #pragma unroll
    for (int j = 0; j < 4; ++j) e[j] = (vf2)(0.f);
    if (odd) {
        #pragma unroll
        for (int j = 0; j < 4; ++j) e[j] = *(const vf2*)(tbl + i1[j]);
    }
    asm volatile(""
        : "+v"(q[0]), "+v"(q[1]), "+v"(q[2]), "+v"(q[3]),
          "+v"(e[0]), "+v"(e[1]), "+v"(e[2]), "+v"(e[3])
        :
        : "memory");

    float ox = 0.f, oy = 0.f;
    #pragma unroll
    for (int j = 0; j < 4; ++j) {
        bool hi = (i0[j] & 1u) != 0u;
        vf2 lo;  lo.x  = q[j].x; lo.y  = q[j].y;
        vf2 hiv; hiv.x = q[j].z; hiv.y = q[j].w;
        vf2 f0 = hi ? hiv : lo;                 // corner x-offset 0
        vf2 f1 = odd ? e[j] : (hi ? lo : hiv);  // corner x-offset 1
        float w0 = wx[0] * wyz[j], w1 = wx[1] * wyz[j];
        ox += w0 * f0.x + w1 * f1.x;
        oy += w0 * f0.y + w1 * f1.y;
    }
    vf2 r; r.x = ox; r.y = oy;
    return r;
}

// ---------- K1: hard levels (6..15) -> ws rows 6..15 ----------
__global__ __launch_bounds__(256) void hashgrid_gather_hard(
    const float* __restrict__ xyz,
    const float* __restrict__ tables,
    const int*   __restrict__ resolutions,
    float*       __restrict__ ws,       // [16][n] float2, as floats
    int n_points)
{
    const int x    = blockIdx.x & 7;    // XCD (blockIdx%8 round-robin)
    const int slot = blockIdx.x >> 3;   // position in XCD x's work queue
    const int C    = (n_points + 511) >> 9;  // 512-point chunks per level

    // Phase 1 (slot < C): level 8+x exclusively (one 4MB table per XCD L2).
    // Phase 2: L7 chunks on XCDs 0-3 (stride 4), L6 chunks on XCDs 4-7.
    //   Each XCD warms exactly ONE cold table; replication 25MB not 50MB.
    int level, chunk;
    if (slot < C) {
        level = 8 + x; chunk = slot;
    } else {
        int j = slot - C;               // phase-2 index, 0..ceil(C/4)-1
        level = (x < 4) ? 7 : 6;
        chunk = (x & 3) + (j << 2);     // stride-4 within the 4-XCD group
    }
    if (chunk >= C) return;

    const float res = (float)resolutions[level];
    const float2* __restrict__ tbl =
        (const float2*)tables + (size_t)level * HG_TABLE_SIZE;
    float* __restrict__ wlev = ws + (size_t)level * n_points * 2;

    const int p0 = (chunk << 9) + ((int)threadIdx.x << 1);   // 2 pts/thread
    if (p0 >= n_points) return;

    if (p0 + 1 < n_points) {
        const float* xp = xyz + (size_t)p0 * 3;
        vf2 c0 = *(const vf2*)(xp);
        vf2 c1 = *(const vf2*)(xp + 2);
        vf2 c2 = *(const vf2*)(xp + 4);

        unsigned sA[4], sB[4], x0A, x0B;
        float wyzA[4], wyzB[4], wxA[2], wxB[2];
        hg_prep2(c0.x, c0.y, c1.x, res, sA, wyzA, &x0A, wxA);
        hg_prep2(c1.y, c2.x, c2.y, res, sB, wyzB, &x0B, wxB);

        unsigned iA0[4], iA1[4], iB0[4], iB1[4];
        #pragma unroll
        for (int j = 0; j < 4; ++j) {
            iA0[j] = (x0A ^ sA[j]) & HG_TABLE_MASK;
            iA1[j] = ((x0A + 1u) ^ sA[j]) & HG_TABLE_MASK;
            iB0[j] = (x0B ^ sB[j]) & HG_TABLE_MASK;
            iB1[j] = ((x0B + 1u) ^ sB[j]) & HG_TABLE_MASK;
        }
        const bool oddA = (x0A & 1u) != 0u;
        const bool oddB = (x0B & 1u) != 0u;

        vf4 qA[4], qB[4];
        #pragma unroll
        for (int j = 0; j < 4; ++j) qA[j] = *(const vf4*)(tbl + (iA0[j] & ~1u));
        #pragma unroll
        for (int j = 0; j < 4; ++j) qB[j] = *(const vf4*)(tbl + (iB0[j] & ~1u));

        vf2 eA[4], eB[4];
        #pragma unroll
        for (int j = 0; j < 4; ++j) { eA[j] = (vf2)(0.f); eB[j] = (vf2)(0.f); }
        if (oddA) {
            #pragma unroll
            for (int j = 0; j < 4; ++j) eA[j] = *(const vf2*)(tbl + iA1[j]);
        }
        if (oddB) {
            #pragma unroll
            for (int j = 0; j < 4; ++j) eB[j] = *(const vf2*)(tbl + iB1[j]);
        }

        asm volatile(""
            : "+v"(qA[0]), "+v"(qA[1]), "+v"(qA[2]), "+v"(qA[3]),
              "+v"(qB[0]), "+v"(qB[1]), "+v"(qB[2]), "+v"(qB[3]),
              "+v"(eA[0]), "+v"(eA[1]), "+v"(eA[2]), "+v"(eA[3]),
              "+v"(eB[0]), "+v"(eB[1]), "+v"(eB[2]), "+v"(eB[3])
            :
            : "memory");

        float oax = 0.f, oay = 0.f, obx = 0.f, oby = 0.f;
        #pragma unroll
        for (int j = 0; j < 4; ++j) {
            bool hi = (iA0[j] & 1u) != 0u;
            vf2 lo;  lo.x  = qA[j].x; lo.y  = qA[j].y;
            vf2 hiv; hiv.x = qA[j].z; hiv.y = qA[j].w;
            vf2 f0 = hi ? hiv : lo;
            vf2 f1 = oddA ? eA[j] : (hi ? lo : hiv);
            float w0 = wxA[0] * wyzA[j], w1 = wxA[1] * wyzA[j];
            oax += w0 * f0.x + w1 * f1.x;
            oay += w0 * f0.y + w1 * f1.y;
        }
        #pragma unroll
        for (int j = 0; j < 4; ++j) {
            bool hi = (iB0[j] & 1u) != 0u;
            vf2 lo;  lo.x  = qB[j].x; lo.y  = qB[j].y;
            vf2 hiv; hiv.x = qB[j].z; hiv.y = qB[j].w;
            vf2 f0 = hi ? hiv : lo;
            vf2 f1 = oddB ? eB[j] : (hi ? lo : hiv);
            float w0 = wxB[0] * wyzB[j], w1 = wxB[1] * wyzB[j];
            obx += w0 * f0.x + w1 * f1.x;
            oby += w0 * f0.y + w1 * f1.y;
        }

        vf4 v; v.x = oax; v.y = oay; v.z = obx; v.w = oby;
        __builtin_nontemporal_store(v, (vf4*)(wlev + 2 * (size_t)p0));
    } else {
        float px = xyz[(size_t)p0 * 3 + 0];
        float py = xyz[(size_t)p0 * 3 + 1];
        float pz = xyz[(size_t)p0 * 3 + 2];
        vf2 v = hg_gather1(tbl, res, px, py, pz);
        __builtin_nontemporal_store(v, (vf2*)(wlev + 2 * (size_t)p0));
    }
}

// ---------- K2: easy gathers (0..5) + ws rows (6..15) -> out [N][16] ----------
#define TP_PTS 256
#define TP_STRIDE (2 * TP_PTS + 4)   // floats per LDS row (pad 4 -> <=2-way conflicts)

__global__ __launch_bounds__(256) void hashgrid_finalize(
    const float* __restrict__ xyz,
    const float* __restrict__ tables,
    const int*   __restrict__ resolutions,
    const float* __restrict__ ws,
    float*       __restrict__ out,
    int n_points)
{
    __shared__ float tile[16 * TP_STRIDE];   // ~33 KB, level-major
    __shared__ float sxyz[3 * TP_PTS];       // 3 KB staged coords
    const int p0 = blockIdx.x * TP_PTS;
    const int t  = (int)threadIdx.x;
    const int npts = min(TP_PTS, n_points - p0);
    const bool full = (npts == TP_PTS);

    // stage xyz: 256 pts * 12B = 3072B = 192 x 16B
    if (full) {
        const vf4* __restrict__ src = (const vf4*)(xyz + (size_t)p0 * 3);
        if (t < 192) ((vf4*)sxyz)[t] = src[t];
    } else {
        for (int p = t; p < npts; p += 256) {
            sxyz[3 * p + 0] = xyz[(size_t)(p0 + p) * 3 + 0];
            sxyz[3 * p + 1] = xyz[(size_t)(p0 + p) * 3 + 1];
            sxyz[3 * p + 2] = xyz[(size_t)(p0 + p) * 3 + 2];
        }
    }

    // cooperative ws rows 6..15 -> tile (1280 vf4 over 256 threads, 5 each)
    #pragma unroll
    for (int k = 0; k < 5; ++k) {
        int idx = t + k * 256;          // [0,1280)
        int r   = 6 + (idx >> 7);       // 6..15
        int q   = idx & 127;            // vf4 index within row (2 pts each)
        int pt  = q * 2;
        if (pt < npts) {
            const float* src = ws + (size_t)r * n_points * 2 + (size_t)(p0 + pt) * 2;
            vf4 v;
            if (pt + 1 < npts) v = __builtin_nontemporal_load((const vf4*)src);
            else { vf2 v2 = __builtin_nontemporal_load((const vf2*)src);
                   v.x = v2.x; v.y = v2.y; v.z = 0.f; v.w = 0.f; }
            *(vf4*)&tile[r * TP_STRIDE + 4 * q] = v;
        }
    }
    __syncthreads();   // sxyz ready

    // easy levels 0..5: thread t gathers point p0+t per level -> tile rows 0..5
    if (t < npts) {
        float px = sxyz[3 * t + 0];
        float py = sxyz[3 * t + 1];
        float pz = sxyz[3 * t + 2];
        #pragma unroll 1
        for (int lev = 0; lev < 6; ++lev) {
            const float res = (float)resolutions[lev];
            const float2* __restrict__ tbl =
                (const float2*)tables + (size_t)lev * HG_TABLE_SIZE;
            vf2 r = hg_gather1p(tbl, res, px, py, pz);
            *(vf2*)&tile[lev * TP_STRIDE + 2 * t] = r;
        }
    }
    __syncthreads();   // tile complete (ws rows + easy rows)

    // transposed write-out: full 128B lines, nt stores (proven path)
    #pragma unroll
    for (int it = 0; it < 8; ++it) {
        int linear = it * 256 + t;
        int pt = linear >> 3;
        int v4 = linear & 7;
        if (pt < npts) {
            vf4 v;
            #pragma unroll
            for (int k = 0; k < 4; ++k) {
                int e = 4 * v4 + k;
                int lev = e >> 1, f = e & 1;
                v[k] = tile[lev * TP_STRIDE + 2 * pt + f];
            }
            __builtin_nontemporal_store(
                v, (vf4*)(out + (size_t)(p0 + pt) * 32 + 4 * v4));
        }
    }
}

// ---------- Fallback: single-kernel version (ws too small) ----------
__global__ __launch_bounds__(256) void hashgrid_fwd(
    const float* __restrict__ xyz,
    const float* __restrict__ tables,
    const int*   __restrict__ resolutions,
    float*       __restrict__ out,
    int n_points)
{
    int tid   = blockIdx.x * blockDim.x + threadIdx.x;
    int point = tid >> 4;
    int level = tid & 15;
    if (point >= n_points) return;

    float px = xyz[point * 3 + 0];
    float py = xyz[point * 3 + 1];
    float pz = xyz[point * 3 + 2];
    float res = (float)resolutions[level];
    const float2* __restrict__ tbl =
        (const float2*)tables + (size_t)level * HG_TABLE_SIZE;

    vf2 v = hg_gather1(tbl, res, px, py, pz);
    *(vf2*)(out + (size_t)point * 32 + 2 * level) = v;
}

extern "C" void kernel_launch(void* const* d_in, const int* in_sizes, int n_in,
                              void* d_out, int out_size, void* d_ws, size_t ws_size,
                              hipStream_t stream) {
    const float* xyz         = (const float*)d_in[0];
    const float* tables      = (const float*)d_in[1];
    const int*   resolutions = (const int*)d_in[2];
    float*       out         = (float*)d_out;

    int n_points = in_sizes[0] / 3;
    size_t ws_needed = (size_t)n_points * HG_N_LEVELS * sizeof(float2);

    if (ws_size >= ws_needed) {
        float* ws = (float*)d_ws;
        int C  = (n_points + 511) >> 9;
        int S2 = (C + 3) >> 2;           // phase-2 slots per XCD (stride-4 split)
        int slots = C + S2;
        hashgrid_gather_hard<<<8 * slots, 256, 0, stream>>>(
            xyz, tables, resolutions, ws, n_points);
        int fblocks = (n_points + TP_PTS - 1) / TP_PTS;
        hashgrid_finalize<<<fblocks, 256, 0, stream>>>(
            xyz, tables, resolutions, ws, out, n_points);
    } else {
        int n_threads = n_points * HG_N_LEVELS;
        hashgrid_fwd<<<(n_threads + 255) / 256, 256, 0, stream>>>(
            xyz, tables, resolutions, out, n_points);
    }
}